// Round 9
// baseline (909.952 us; speedup 1.0000x reference)
//
#include <hip/hip_runtime.h>
#include <stdint.h>

// Hashgrid encoder, L=16, D=3, C=2, H=16, S=1.
// R8: one launch PER LEVEL (phase-locked level sweep). R6/R7 pinned at
// ~3.5 TB/s fabric random-64B: each XCD's 4MB L2 faces a 52MB working set.
// Launch-serialized per-level sweeps shrink the instantaneous working set
// to ONE 4MB table -> L2-resident per XCD. Phases write level-major float2
// to d_ws (coalesced nt stores); a final kernel transposes to point-major.

constexpr uint32_t OFF[16] = {
    0u, 4920u, 40864u, 315496u, 839784u, 1364072u, 1888360u, 2412648u,
    2936936u, 3461224u, 3985512u, 4509800u, 5034088u, 5558376u, 6082664u, 6606952u
};

#define HASH_ENTRIES 524288u
#define HASH_MASK    (HASH_ENTRIES - 1u)
#define P1 2654435761u
#define P2 805459861u

typedef float floatx2 __attribute__((ext_vector_type(2)));
typedef float floatx4 __attribute__((ext_vector_type(4)));

template<int L, bool DIRECT>
__global__ __launch_bounds__(256) void phase_kernel(
    const float* __restrict__ xyz,
    const float2* __restrict__ ext,   // 524288 entries
    const float2* __restrict__ own,   // remaining entries
    float* __restrict__ dst,          // ws (level-major) or out (DIRECT)
    int B)
{
    const int b = blockIdx.x * 256 + threadIdx.x;
    if (b >= B) return;

    // nt loads: xyz streams; don't let it evict the table from L2.
    const float x01 = (__builtin_nontemporal_load(&xyz[3 * b + 0]) + 1.0f) * 0.5f;
    const float y01 = (__builtin_nontemporal_load(&xyz[3 * b + 1]) + 1.0f) * 0.5f;
    const float z01 = (__builtin_nontemporal_load(&xyz[3 * b + 2]) + 1.0f) * 0.5f;

    constexpr float scale = (float)((16u << L) - 1u);   // exact in fp32
    const float px = x01 * scale + 0.5f;
    const float py = y01 * scale + 0.5f;
    const float pz = z01 * scale + 0.5f;
    const float fxf = floorf(px), fyf = floorf(py), fzf = floorf(pz);
    const float tx = px - fxf, ty = py - fyf, tz = pz - fzf;
    const uint32_t x0 = (uint32_t)(int)fxf;
    const uint32_t y0 = (uint32_t)(int)fyf;
    const uint32_t z0 = (uint32_t)(int)fzf;

    float2 f[8];
    if constexpr (L < 3) {
        // dense: index provably < hashmap size; whole level inside ext
        constexpr uint32_t side = (16u << L) + 1u;
        constexpr uint32_t s2 = side * side;
        const uint32_t base = OFF[L] + x0 + y0 * side + z0 * s2;
#pragma unroll
        for (int i = 0; i < 8; ++i) {
            f[i] = ext[base + (uint32_t)(i & 1)
                           + (uint32_t)((i >> 1) & 1) * side
                           + (uint32_t)((i >> 2) & 1) * s2];
        }
    } else {
        const uint32_t hx0 = x0,       hx1 = x0 + 1u;   // PRIMES[0]==1
        const uint32_t hy0 = y0 * P1,  hy1 = (y0 + 1u) * P1;
        const uint32_t hz0 = z0 * P2,  hz1 = (z0 + 1u) * P2;
#pragma unroll
        for (int i = 0; i < 8; ++i) {
            const uint32_t gi = (((i & 1) ? hx1 : hx0) ^
                                 ((i & 2) ? hy1 : hy0) ^
                                 ((i & 4) ? hz1 : hz0)) & HASH_MASK;
            if constexpr (L == 3) {
                // level 3 straddles the ext/own boundary at 524288
                const uint32_t gg = gi + OFF[3];
                const float2* p = (gg < HASH_ENTRIES)
                                    ? (ext + gg)
                                    : (own + (gg - HASH_ENTRIES));
                f[i] = *p;
            } else {
                f[i] = own[(OFF[L] - HASH_ENTRIES) + gi];
            }
        }
    }

    float r0 = 0.0f, r1 = 0.0f;
#pragma unroll
    for (int i = 0; i < 8; ++i) {
        const float wi = ((i & 1) ? tx : 1.0f - tx)
                       * ((i & 2) ? ty : 1.0f - ty)
                       * ((i & 4) ? tz : 1.0f - tz);
        r0 += wi * f[i].x;
        r1 += wi * f[i].y;
    }

    floatx2 v = { r0, r1 };
    if constexpr (DIRECT) {
        __builtin_nontemporal_store(v, (floatx2*)(dst + (size_t)b * 32 + 2 * L));
    } else {
        // level-major: contiguous per phase -> full-line coalesced nt writes
        __builtin_nontemporal_store(v, (floatx2*)(dst + (size_t)L * 2 * B + 2 * b));
    }
}

__global__ __launch_bounds__(256) void transpose_kernel(
    const float* __restrict__ ws, float* __restrict__ out, int B)
{
    const int b = blockIdx.x * 256 + threadIdx.x;
    if (b >= B) return;
    float v[32];
#pragma unroll
    for (int l = 0; l < 16; ++l) {
        floatx2 t = __builtin_nontemporal_load(
            (const floatx2*)(ws + (size_t)l * 2 * B + 2 * b));
        v[2 * l + 0] = t.x;
        v[2 * l + 1] = t.y;
    }
    floatx4* o4 = (floatx4*)(out + (size_t)b * 32);
#pragma unroll
    for (int k = 0; k < 8; ++k) {
        floatx4 q = { v[4 * k + 0], v[4 * k + 1], v[4 * k + 2], v[4 * k + 3] };
        __builtin_nontemporal_store(q, &o4[k]);
    }
}

template<bool DIRECT>
static inline void launch_phases(const float* xyz, const float2* ext,
                                 const float2* own, float* dst, int B,
                                 int grid, hipStream_t stream) {
    phase_kernel< 0, DIRECT><<<grid, 256, 0, stream>>>(xyz, ext, own, dst, B);
    phase_kernel< 1, DIRECT><<<grid, 256, 0, stream>>>(xyz, ext, own, dst, B);
    phase_kernel< 2, DIRECT><<<grid, 256, 0, stream>>>(xyz, ext, own, dst, B);
    phase_kernel< 3, DIRECT><<<grid, 256, 0, stream>>>(xyz, ext, own, dst, B);
    phase_kernel< 4, DIRECT><<<grid, 256, 0, stream>>>(xyz, ext, own, dst, B);
    phase_kernel< 5, DIRECT><<<grid, 256, 0, stream>>>(xyz, ext, own, dst, B);
    phase_kernel< 6, DIRECT><<<grid, 256, 0, stream>>>(xyz, ext, own, dst, B);
    phase_kernel< 7, DIRECT><<<grid, 256, 0, stream>>>(xyz, ext, own, dst, B);
    phase_kernel< 8, DIRECT><<<grid, 256, 0, stream>>>(xyz, ext, own, dst, B);
    phase_kernel< 9, DIRECT><<<grid, 256, 0, stream>>>(xyz, ext, own, dst, B);
    phase_kernel<10, DIRECT><<<grid, 256, 0, stream>>>(xyz, ext, own, dst, B);
    phase_kernel<11, DIRECT><<<grid, 256, 0, stream>>>(xyz, ext, own, dst, B);
    phase_kernel<12, DIRECT><<<grid, 256, 0, stream>>>(xyz, ext, own, dst, B);
    phase_kernel<13, DIRECT><<<grid, 256, 0, stream>>>(xyz, ext, own, dst, B);
    phase_kernel<14, DIRECT><<<grid, 256, 0, stream>>>(xyz, ext, own, dst, B);
    phase_kernel<15, DIRECT><<<grid, 256, 0, stream>>>(xyz, ext, own, dst, B);
}

extern "C" void kernel_launch(void* const* d_in, const int* in_sizes, int n_in,
                              void* d_out, int out_size, void* d_ws, size_t ws_size,
                              hipStream_t stream) {
    const float*  xyz = (const float*)d_in[0];
    const float2* ext = (const float2*)d_in[1];
    const float2* own = (const float2*)d_in[2];
    float* out = (float*)d_out;
    const int B = in_sizes[0] / 3;
    const int grid = (B + 255) / 256;

    const size_t need = (size_t)B * 32 * sizeof(float);
    if (ws_size >= need) {
        float* ws = (float*)d_ws;
        launch_phases<false>(xyz, ext, own, ws, B, grid, stream);
        transpose_kernel<<<grid, 256, 0, stream>>>(ws, out, B);
    } else {
        launch_phases<true>(xyz, ext, own, out, B, grid, stream);
    }
}

// Round 12
// 662.774 us; speedup vs baseline: 1.3729x; 1.3729x over previous
//
#include <hip/hip_runtime.h>
#include <hip/hip_cooperative_groups.h>
#include <stdint.h>

namespace cg = cooperative_groups;

// Hashgrid encoder, L=16, D=3, C=2, H=16, S=1.
// R10: single cooperative kernel, grid.sync() between levels = structural
// phase-lock (R9 proved per-level serialization beats the ~3.5TB/s fabric
// wall: phases 575us vs 753us monolithic), with the R9 transpose disaster
// (335us from 16B nt partial-line writes) replaced by an in-kernel
// transpose using PLAIN stores (R6 evidence: plain stores merge, 131MB).

constexpr uint32_t OFF[16] = {
    0u, 4920u, 40864u, 315496u, 839784u, 1364072u, 1888360u, 2412648u,
    2936936u, 3461224u, 3985512u, 4509800u, 5034088u, 5558376u, 6082664u, 6606952u
};

#define HASH_ENTRIES 524288u
#define HASH_MASK    (HASH_ENTRIES - 1u)
#define P1 2654435761u
#define P2 805459861u

typedef float floatx2 __attribute__((ext_vector_type(2)));
typedef float floatx4 __attribute__((ext_vector_type(4)));

// ---- per-level gather+interp, level is compile-time ----
template<int L>
__device__ __forceinline__ void do_level(
    float x01, float y01, float z01,
    const float2* __restrict__ ext, const float2* __restrict__ own,
    float* __restrict__ ws, int B, int p)
{
    constexpr float scale = (float)((16u << L) - 1u);   // exact in fp32
    const float px = x01 * scale + 0.5f;
    const float py = y01 * scale + 0.5f;
    const float pz = z01 * scale + 0.5f;
    const float fxf = floorf(px), fyf = floorf(py), fzf = floorf(pz);
    const float tx = px - fxf, ty = py - fyf, tz = pz - fzf;
    const uint32_t x0 = (uint32_t)(int)fxf;
    const uint32_t y0 = (uint32_t)(int)fyf;
    const uint32_t z0 = (uint32_t)(int)fzf;

    float2 f[8];
    if constexpr (L < 3) {
        constexpr uint32_t side = (16u << L) + 1u;
        constexpr uint32_t s2 = side * side;
        const uint32_t base = OFF[L] + x0 + y0 * side + z0 * s2;
#pragma unroll
        for (int i = 0; i < 8; ++i) {
            f[i] = ext[base + (uint32_t)(i & 1)
                           + (uint32_t)((i >> 1) & 1) * side
                           + (uint32_t)((i >> 2) & 1) * s2];
        }
    } else {
        const uint32_t hx0 = x0,       hx1 = x0 + 1u;   // PRIMES[0]==1
        const uint32_t hy0 = y0 * P1,  hy1 = (y0 + 1u) * P1;
        const uint32_t hz0 = z0 * P2,  hz1 = (z0 + 1u) * P2;
#pragma unroll
        for (int i = 0; i < 8; ++i) {
            const uint32_t gi = (((i & 1) ? hx1 : hx0) ^
                                 ((i & 2) ? hy1 : hy0) ^
                                 ((i & 4) ? hz1 : hz0)) & HASH_MASK;
            if constexpr (L == 3) {
                const uint32_t gg = gi + OFF[3];   // straddles ext/own split
                const float2* q = (gg < HASH_ENTRIES)
                                    ? (ext + gg)
                                    : (own + (gg - HASH_ENTRIES));
                f[i] = *q;
            } else {
                f[i] = own[(OFF[L] - HASH_ENTRIES) + gi];
            }
        }
    }

    float r0 = 0.0f, r1 = 0.0f;
#pragma unroll
    for (int i = 0; i < 8; ++i) {
        const float wi = ((i & 1) ? tx : 1.0f - tx)
                       * ((i & 2) ? ty : 1.0f - ty)
                       * ((i & 4) ? tz : 1.0f - tz);
        r0 += wi * f[i].x;
        r1 += wi * f[i].y;
    }
    // level-major, full-line coalesced; nt keeps the hash table in L2
    floatx2 v = { r0, r1 };
    __builtin_nontemporal_store(v, (floatx2*)(ws + (size_t)L * 2 * B + 2 * p));
}

// ---- cooperative all-levels kernel: 4 points/thread, sync between levels ----
__global__ __launch_bounds__(256, 4) void coop_kernel(
    const float* __restrict__ xyz,
    const float2* __restrict__ ext,
    const float2* __restrict__ own,
    float* __restrict__ ws,
    float* __restrict__ out,
    int B)
{
    cg::grid_group grid = cg::this_grid();
    const int NT  = (int)(gridDim.x * 256u);
    const int tid = (int)(blockIdx.x * 256u + threadIdx.x);

    // cache coords for the thread's (up to) 4 points in registers
    float cx[4], cy[4], cz[4];
#pragma unroll
    for (int i = 0; i < 4; ++i) {
        const int p = tid + i * NT;
        if (p < B) {
            cx[i] = (__builtin_nontemporal_load(&xyz[3 * p + 0]) + 1.0f) * 0.5f;
            cy[i] = (__builtin_nontemporal_load(&xyz[3 * p + 1]) + 1.0f) * 0.5f;
            cz[i] = (__builtin_nontemporal_load(&xyz[3 * p + 2]) + 1.0f) * 0.5f;
        } else {
            cx[i] = cy[i] = cz[i] = 0.0f;
        }
    }

#define LEVEL_STEP(L)                                                        \
    {                                                                        \
        _Pragma("unroll")                                                    \
        for (int i = 0; i < 4; ++i) {                                        \
            const int p = tid + i * NT;                                      \
            if (p < B) do_level<L>(cx[i], cy[i], cz[i], ext, own, ws, B, p); \
        }                                                                    \
        grid.sync();                                                         \
    }

    LEVEL_STEP(0)  LEVEL_STEP(1)  LEVEL_STEP(2)  LEVEL_STEP(3)
    LEVEL_STEP(4)  LEVEL_STEP(5)  LEVEL_STEP(6)  LEVEL_STEP(7)
    LEVEL_STEP(8)  LEVEL_STEP(9)  LEVEL_STEP(10) LEVEL_STEP(11)
    LEVEL_STEP(12) LEVEL_STEP(13) LEVEL_STEP(14) LEVEL_STEP(15)
#undef LEVEL_STEP

    // in-kernel transpose: each thread gathers its OWN points' level-major
    // rows -> one contiguous 128B record. PLAIN stores (L2 merges full
    // lines; nt here caused R9's 3x write amplification).
#pragma unroll
    for (int i = 0; i < 4; ++i) {
        const int p = tid + i * NT;
        if (p >= B) continue;
        float v[32];
#pragma unroll
        for (int l = 0; l < 16; ++l) {
            floatx2 t = *(const floatx2*)(ws + (size_t)l * 2 * B + 2 * p);
            v[2 * l + 0] = t.x;
            v[2 * l + 1] = t.y;
        }
        floatx4* o4 = (floatx4*)(out + (size_t)p * 32);
#pragma unroll
        for (int k = 0; k < 8; ++k) {
            floatx4 q = { v[4 * k + 0], v[4 * k + 1],
                          v[4 * k + 2], v[4 * k + 3] };
            o4[k] = q;
        }
    }
}

// ---- fallback path: 16 per-level launches + separate transpose ----
template<int L, bool DIRECT>
__global__ __launch_bounds__(256) void phase_kernel(
    const float* __restrict__ xyz,
    const float2* __restrict__ ext,
    const float2* __restrict__ own,
    float* __restrict__ dst,
    int B)
{
    const int b = blockIdx.x * 256 + threadIdx.x;
    if (b >= B) return;
    const float x01 = (__builtin_nontemporal_load(&xyz[3 * b + 0]) + 1.0f) * 0.5f;
    const float y01 = (__builtin_nontemporal_load(&xyz[3 * b + 1]) + 1.0f) * 0.5f;
    const float z01 = (__builtin_nontemporal_load(&xyz[3 * b + 2]) + 1.0f) * 0.5f;
    if constexpr (DIRECT) {
        constexpr float scale = (float)((16u << L) - 1u);
        const float px = x01 * scale + 0.5f;
        const float py = y01 * scale + 0.5f;
        const float pz = z01 * scale + 0.5f;
        const float fxf = floorf(px), fyf = floorf(py), fzf = floorf(pz);
        const float tx = px - fxf, ty = py - fyf, tz = pz - fzf;
        const uint32_t x0 = (uint32_t)(int)fxf;
        const uint32_t y0 = (uint32_t)(int)fyf;
        const uint32_t z0 = (uint32_t)(int)fzf;
        float2 f[8];
        if constexpr (L < 3) {
            constexpr uint32_t side = (16u << L) + 1u;
            constexpr uint32_t s2 = side * side;
            const uint32_t base = OFF[L] + x0 + y0 * side + z0 * s2;
#pragma unroll
            for (int i = 0; i < 8; ++i)
                f[i] = ext[base + (uint32_t)(i & 1)
                               + (uint32_t)((i >> 1) & 1) * side
                               + (uint32_t)((i >> 2) & 1) * s2];
        } else {
            const uint32_t hx0 = x0,       hx1 = x0 + 1u;
            const uint32_t hy0 = y0 * P1,  hy1 = (y0 + 1u) * P1;
            const uint32_t hz0 = z0 * P2,  hz1 = (z0 + 1u) * P2;
#pragma unroll
            for (int i = 0; i < 8; ++i) {
                const uint32_t gi = (((i & 1) ? hx1 : hx0) ^
                                     ((i & 2) ? hy1 : hy0) ^
                                     ((i & 4) ? hz1 : hz0)) & HASH_MASK;
                if constexpr (L == 3) {
                    const uint32_t gg = gi + OFF[3];
                    const float2* q = (gg < HASH_ENTRIES)
                                        ? (ext + gg)
                                        : (own + (gg - HASH_ENTRIES));
                    f[i] = *q;
                } else {
                    f[i] = own[(OFF[L] - HASH_ENTRIES) + gi];
                }
            }
        }
        float r0 = 0.0f, r1 = 0.0f;
#pragma unroll
        for (int i = 0; i < 8; ++i) {
            const float wi = ((i & 1) ? tx : 1.0f - tx)
                           * ((i & 2) ? ty : 1.0f - ty)
                           * ((i & 4) ? tz : 1.0f - tz);
            r0 += wi * f[i].x;
            r1 += wi * f[i].y;
        }
        floatx2 v = { r0, r1 };
        *(floatx2*)(dst + (size_t)b * 32 + 2 * L) = v;
    } else {
        do_level<L>(x01, y01, z01, ext, own, dst, B, b);
    }
}

__global__ __launch_bounds__(256) void transpose_kernel(
    const float* __restrict__ ws, float* __restrict__ out, int B)
{
    const int b = blockIdx.x * 256 + threadIdx.x;
    if (b >= B) return;
    float v[32];
#pragma unroll
    for (int l = 0; l < 16; ++l) {
        floatx2 t = *(const floatx2*)(ws + (size_t)l * 2 * B + 2 * b);
        v[2 * l + 0] = t.x;
        v[2 * l + 1] = t.y;
    }
    floatx4* o4 = (floatx4*)(out + (size_t)b * 32);
#pragma unroll
    for (int k = 0; k < 8; ++k) {
        floatx4 q = { v[4 * k + 0], v[4 * k + 1], v[4 * k + 2], v[4 * k + 3] };
        o4[k] = q;   // plain stores: L2 merges into full lines
    }
}

template<bool DIRECT>
static inline void launch_phases(const float* xyz, const float2* ext,
                                 const float2* own, float* dst, int B,
                                 int grid, hipStream_t stream) {
    phase_kernel< 0, DIRECT><<<grid, 256, 0, stream>>>(xyz, ext, own, dst, B);
    phase_kernel< 1, DIRECT><<<grid, 256, 0, stream>>>(xyz, ext, own, dst, B);
    phase_kernel< 2, DIRECT><<<grid, 256, 0, stream>>>(xyz, ext, own, dst, B);
    phase_kernel< 3, DIRECT><<<grid, 256, 0, stream>>>(xyz, ext, own, dst, B);
    phase_kernel< 4, DIRECT><<<grid, 256, 0, stream>>>(xyz, ext, own, dst, B);
    phase_kernel< 5, DIRECT><<<grid, 256, 0, stream>>>(xyz, ext, own, dst, B);
    phase_kernel< 6, DIRECT><<<grid, 256, 0, stream>>>(xyz, ext, own, dst, B);
    phase_kernel< 7, DIRECT><<<grid, 256, 0, stream>>>(xyz, ext, own, dst, B);
    phase_kernel< 8, DIRECT><<<grid, 256, 0, stream>>>(xyz, ext, own, dst, B);
    phase_kernel< 9, DIRECT><<<grid, 256, 0, stream>>>(xyz, ext, own, dst, B);
    phase_kernel<10, DIRECT><<<grid, 256, 0, stream>>>(xyz, ext, own, dst, B);
    phase_kernel<11, DIRECT><<<grid, 256, 0, stream>>>(xyz, ext, own, dst, B);
    phase_kernel<12, DIRECT><<<grid, 256, 0, stream>>>(xyz, ext, own, dst, B);
    phase_kernel<13, DIRECT><<<grid, 256, 0, stream>>>(xyz, ext, own, dst, B);
    phase_kernel<14, DIRECT><<<grid, 256, 0, stream>>>(xyz, ext, own, dst, B);
    phase_kernel<15, DIRECT><<<grid, 256, 0, stream>>>(xyz, ext, own, dst, B);
}

extern "C" void kernel_launch(void* const* d_in, const int* in_sizes, int n_in,
                              void* d_out, int out_size, void* d_ws, size_t ws_size,
                              hipStream_t stream) {
    const float*  xyz = (const float*)d_in[0];
    const float2* ext = (const float2*)d_in[1];
    const float2* own = (const float2*)d_in[2];
    float* out = (float*)d_out;
    const int B = in_sizes[0] / 3;
    const int grid = (B + 255) / 256;
    const size_t need = (size_t)B * 32 * sizeof(float);

    // Co-residency check for the cooperative path (deterministic per call).
    int dev = 0;
    hipGetDevice(&dev);
    int cus = 0;
    hipDeviceGetAttribute(&cus, hipDeviceAttributeMultiprocessorCount, dev);
    int occ = 0;
    hipOccupancyMaxActiveBlocksPerMultiprocessor(&occ, coop_kernel, 256, 0);
    const int gridNeeded = (B + 4 * 256 - 1) / (4 * 256);   // 4 points/thread

    if (ws_size >= need && occ > 0 && (long)occ * cus >= gridNeeded) {
        float* ws = (float*)d_ws;
        int Bv = B;
        void* args[6];
        args[0] = (void*)&xyz; args[1] = (void*)&ext; args[2] = (void*)&own;
        args[3] = (void*)&ws;  args[4] = (void*)&out; args[5] = (void*)&Bv;
        hipLaunchCooperativeKernel((const void*)coop_kernel,
                                   dim3(gridNeeded), dim3(256), args, 0, stream);
    } else if (ws_size >= need) {
        float* ws = (float*)d_ws;
        launch_phases<false>(xyz, ext, own, ws, B, grid, stream);
        transpose_kernel<<<grid, 256, 0, stream>>>(ws, out, B);
    } else {
        launch_phases<true>(xyz, ext, own, out, B, grid, stream);
    }
}